// Round 7
// baseline (388.721 us; speedup 1.0000x reference)
//
#include <hip/hip_runtime.h>
#include <stdint.h>
#include <stddef.h>

#define M_DIM 8192
#define N_DIM 4096
#define K_DIM 4096

#define BM 256   // R11: taller A-tile; wave tile 128x64, acc[8][4]
#define BN 128
#define BK 128   // int8: BK bytes per row-tile

typedef int i32x4 __attribute__((ext_vector_type(4)));

__device__ __forceinline__ void async_load16(void* lds, const void* g) {
  __builtin_amdgcn_global_load_lds(
      (const __attribute__((address_space(1))) void*)g,
      (__attribute__((address_space(3))) void*)lds,
      16, 0, 0);
}

// R10 fused aux: quant_x (blocks [0,8192)) + pack_w (blocks [8192,12288)).
// UNCHANGED (control; did not surface in top-5 => combined < ~134 us).
__global__ void fused_aux_kernel(const float* __restrict__ x,
                                 signed char* __restrict__ xq,
                                 float* __restrict__ xs,
                                 const int* __restrict__ w,
                                 signed char* __restrict__ wp) {
  const int t = threadIdx.x;
  if (blockIdx.x < M_DIM) {
    const int row = blockIdx.x;
    const float4* xr = (const float4*)(x + (size_t)row * K_DIM);
    float4 v[4];
    float m = 0.f;
#pragma unroll
    for (int r = 0; r < 4; ++r) {
      v[r] = xr[r * 256 + t];                       // coalesced 16B/lane
      m = fmaxf(m, fmaxf(fmaxf(fabsf(v[r].x), fabsf(v[r].y)),
                         fmaxf(fabsf(v[r].z), fabsf(v[r].w))));
    }
#pragma unroll
    for (int off = 32; off > 0; off >>= 1)
      m = fmaxf(m, __shfl_down(m, off, 64));
    __shared__ float wmax[4];
    if ((t & 63) == 0) wmax[t >> 6] = m;
    __syncthreads();
    float rowmax = fmaxf(fmaxf(wmax[0], wmax[1]), fmaxf(wmax[2], wmax[3]));
    float inv = rowmax > 0.f ? 127.0f / rowmax : 0.f;
    if (t == 0) xs[row] = rowmax > 0.f ? rowmax * (1.0f / 127.0f) : 0.f;
    uint* oq = (uint*)(xq + (size_t)row * K_DIM);
#pragma unroll
    for (int r = 0; r < 4; ++r) {
      union { signed char c[4]; uint u; } o;
      o.c[0] = (signed char)(int)rintf(v[r].x * inv);
      o.c[1] = (signed char)(int)rintf(v[r].y * inv);
      o.c[2] = (signed char)(int)rintf(v[r].z * inv);
      o.c[3] = (signed char)(int)rintf(v[r].w * inv);
      oq[r * 256 + t] = o.u;                        // coalesced 4B/lane
    }
  } else {
    const int4* wi = (const int4*)w;
    uint* wo = (uint*)wp;
    size_t base = (size_t)(blockIdx.x - M_DIM) * 1024 + t;   // int4-chunk idx
#pragma unroll
    for (int r = 0; r < 4; ++r) {
      int4 a = wi[base + r * 256];
      union { signed char c[4]; uint u; } o;
      o.c[0] = (signed char)a.x; o.c[1] = (signed char)a.y;
      o.c[2] = (signed char)a.z; o.c[3] = (signed char)a.w;
      wo[base + r * 256] = o.u;
    }
  }
}

// C[M,N] = sum_k Aq[m,k]*Bq[n,k] * xs[m] * scaler[n], int8 MFMA 16x16x64.
// R11: 256x128 block tile, 4 waves of 128x64 each (acc[8][4]).
// Rationale (DS-pipe model): the per-CU DS pipe (256 B/clk ~ 4 cyc per
// wave64 ds_read_b128) is shared by 4 MFMA-issuing SIMDs. At acc[4][4]
// (0.5 reads/MFMA) demand is 1.57x the pipe -> ~64% MfmaUtil ceiling
// (we measured 49%). acc[8][4] = 0.375 reads/MFMA -> ceiling ~85%.
// Cost: acc=128 VGPR -> ~2 blocks/CU (8 waves); compute per barrier
// doubles so each barrier hides half the relative latency.
// Per-instruction LDS read pattern (16 rows x 4 quads, XOR chunk swizzle)
// is IDENTICAL to the 0-conflict R0 geometry.
__global__ __launch_bounds__(256, 2) void gemm_i8(
    const signed char* __restrict__ Aq, const signed char* __restrict__ Bq,
    const float* __restrict__ xs, const float* __restrict__ scaler,
    float* __restrict__ C) {
  __shared__ __align__(16) uint8_t sA[BM * BK];  // 32 KiB
  __shared__ __align__(16) uint8_t sB[BN * BK];  // 16 KiB

  // XCD-grouped mapping: 1024 blocks = 8 xcd x 128 slots.
  // tile_n in [0,32)*128, tile_m in [0,32)*256.
  const int bid  = blockIdx.x;
  const int xcd  = bid & 7;
  const int slot = bid >> 3;
  const int tile_n = (xcd * 4 + (slot & 3)) * BN;
  const int tile_m = (slot >> 2) * BM;

  const int w    = threadIdx.x >> 6;
  const int lane = threadIdx.x & 63;
  const int q    = lane >> 4;
  const int m16  = lane & 15;
  const int wrow = (w >> 1) * 128;   // wave M-offset (2 waves stack in M)
  const int wcol = (w & 1) * 64;     // wave N-offset

  i32x4 acc[8][4];
#pragma unroll
  for (int i = 0; i < 8; ++i)
#pragma unroll
    for (int j = 0; j < 4; ++j)
      acc[i][j] = (i32x4){0, 0, 0, 0};

  for (int kt = 0; kt < K_DIM; kt += BK) {
    // Stage A: 2048 16B-chunks (8 rounds), B: 1024 (4 rounds).
    // Slot g: r = g>>3, c = (g&7) ^ (r&7); lds addr = wave-uniform base
    // + lane*16 (global_load_lds constraint). 0 conflicts measured.
#pragma unroll
    for (int p = 0; p < 8; ++p) {
      int g = ((p * 4 + w) << 6) + lane;
      int r = g >> 3;
      int c = (g & 7) ^ (r & 7);
      async_load16(sA + (size_t)g * 16,
                   Aq + (size_t)(tile_m + r) * K_DIM + kt + c * 16);
    }
#pragma unroll
    for (int p = 0; p < 4; ++p) {
      int g = ((p * 4 + w) << 6) + lane;
      int r = g >> 3;
      int c = (g & 7) ^ (r & 7);
      async_load16(sB + (size_t)g * 16,
                   Bq + (size_t)(tile_n + r) * K_DIM + kt + c * 16);
    }
    __syncthreads();

#pragma unroll
    for (int ks = 0; ks < 2; ++ks) {
      const int ck = (ks << 2) + q;   // chunk index 0..7 = K bytes [ck*16,+16)
      i32x4 af[8], bfr[4];
#pragma unroll
      for (int t = 0; t < 8; ++t) {
        int ra = wrow + t * 16 + m16;
        af[t] = *(const i32x4*)(sA + (size_t)(((ra << 3) + (ck ^ (ra & 7))) << 4));
      }
#pragma unroll
      for (int t = 0; t < 4; ++t) {
        int rb = wcol + t * 16 + m16;
        bfr[t] = *(const i32x4*)(sB + (size_t)(((rb << 3) + (ck ^ (rb & 7))) << 4));
      }
#pragma unroll
      for (int i = 0; i < 8; ++i)
#pragma unroll
        for (int j = 0; j < 4; ++j)
          acc[i][j] = __builtin_amdgcn_mfma_i32_16x16x64_i8(
              af[i], bfr[j], acc[i][j], 0, 0, 0);
    }
    __syncthreads();
  }

  // Epilogue: C/D col=lane&15, row=(lane>>4)*4+reg (verified layout).
  float rs[8][4];
#pragma unroll
  for (int i = 0; i < 8; ++i)
#pragma unroll
    for (int r = 0; r < 4; ++r)
      rs[i][r] = xs[tile_m + wrow + i * 16 + q * 4 + r];
#pragma unroll
  for (int j = 0; j < 4; ++j) {
    int col = tile_n + wcol + j * 16 + m16;
    float s = scaler[col];
#pragma unroll
    for (int i = 0; i < 8; ++i) {
      int row0 = tile_m + wrow + i * 16 + q * 4;
#pragma unroll
      for (int r = 0; r < 4; ++r)
        C[(size_t)(row0 + r) * N_DIM + col] = (float)acc[i][j][r] * rs[i][r] * s;
    }
  }
}

// Correct-but-slow insurance if ws_size is too small.
__global__ void fallback_kernel(const float* __restrict__ x,
                                const int* __restrict__ wq,
                                const float* __restrict__ s,
                                float* __restrict__ out) {
  size_t idx = (size_t)blockIdx.x * blockDim.x + threadIdx.x;
  int m = (int)(idx / N_DIM), n = (int)(idx % N_DIM);
  const float* xr = x + (size_t)m * K_DIM;
  const int* wr = wq + (size_t)n * K_DIM;
  float acc = 0.f;
  for (int k = 0; k < K_DIM; ++k) acc += xr[k] * (float)wr[k];
  out[idx] = acc * s[n];
}

extern "C" void kernel_launch(void* const* d_in, const int* in_sizes, int n_in,
                              void* d_out, int out_size, void* d_ws, size_t ws_size,
                              hipStream_t stream) {
  const float* x = (const float*)d_in[0];
  const int* wq = (const int*)d_in[1];   // int32 (verified R2)
  const float* sc = (const float*)d_in[2];
  float* out = (float*)d_out;

  const size_t nx = (size_t)M_DIM * K_DIM;   // 33,554,432
  const size_t nw = (size_t)N_DIM * K_DIM;   // 16,777,216
  const size_t off_xq = 32768;               // xs: 8192 floats
  const size_t off_wp = off_xq + nx;
  const size_t need = off_wp + nw;           // ~50.4 MB

  if (ws_size < need) {
    size_t total = (size_t)M_DIM * N_DIM;
    fallback_kernel<<<(int)(total / 256), 256, 0, stream>>>(x, wq, sc, out);
    return;
  }

  float* xs = (float*)d_ws;
  signed char* xq = (signed char*)d_ws + off_xq;
  signed char* wp = (signed char*)d_ws + off_wp;

  // One fused aux dispatch: 8192 quant blocks + 4096 pack blocks.
  fused_aux_kernel<<<M_DIM + (int)(nw / 4 / 1024), 256, 0, stream>>>(
      x, xq, xs, wq, wp);

  // 32 x 32 = 1024 tiles of 256x128.
  gemm_i8<<<(N_DIM / BN) * (M_DIM / BM), 256, 0, stream>>>(xq, wp, xs, sc, out);
}